// Round 4
// baseline (1184.487 us; speedup 1.0000x reference)
//
#include <hip/hip_runtime.h>

#define MDIM 64

typedef const __attribute__((address_space(1))) void gv_t;
typedef __attribute__((address_space(3))) void lv_t;

__device__ __forceinline__ void cp16(const float* g, float* l) {
  __builtin_amdgcn_global_load_lds((gv_t*)g, (lv_t*)l, 16, 0, 0);
}

// ---------------- Kernel 1: partial Gram G = X^T X ----------------
// 256 thr = 4 waves. Wave w computes G rows [16w,16w+16); lane = column.
// X chunk (64 rows) staged in LDS (linear, unpadded -> global_load_lds ok),
// double-buffered. A-operand via uniform scalar loads (SMEM), B via ds_read_b32.
__global__ __launch_bounds__(256) void k_gram(const float* __restrict__ X,
                                              float* __restrict__ partials,
                                              int N, int rpb) {
  __shared__ float xs[2][4096];
  const int t = threadIdx.x;
  const int lane = t & 63;
  const int wave = __builtin_amdgcn_readfirstlane(t >> 6);  // provably uniform

  long row0 = (long)blockIdx.x * rpb;
  long rowEnd = row0 + rpb;
  if (rowEnd > N) rowEnd = N;
  long nrow = rowEnd - row0;
  int nchunk = (int)((nrow + 63) >> 6);

  float acc[16];
#pragma unroll
  for (int i = 0; i < 16; ++i) acc[i] = 0.f;

  if (nchunk > 0) {
    // stage chunk 0
#pragma unroll
    for (int i = 0; i < 4; ++i) {
      int slot = i * 256 + t;                 // float4 slot 0..1023
      long gr = row0 + (slot >> 4);
      if (gr < rowEnd) cp16(X + gr * 64 + (slot & 15) * 4, &xs[0][slot * 4]);
      else *reinterpret_cast<float4*>(&xs[0][slot * 4]) = make_float4(0, 0, 0, 0);
    }

    for (int c = 0; c < nchunk; ++c) {
      int cur = c & 1;
      bool more = (c + 1 < nchunk);
      if (more) {
        long r0n = row0 + (long)(c + 1) * 64;
#pragma unroll
        for (int i = 0; i < 4; ++i) {
          int slot = i * 256 + t;
          long gr = r0n + (slot >> 4);
          if (gr < rowEnd) cp16(X + gr * 64 + (slot & 15) * 4, &xs[cur ^ 1][slot * 4]);
          else *reinterpret_cast<float4*>(&xs[cur ^ 1][slot * 4]) = make_float4(0, 0, 0, 0);
        }
        asm volatile("s_waitcnt vmcnt(4) lgkmcnt(0)" ::: "memory");  // cur done, next in flight
      } else {
        asm volatile("s_waitcnt vmcnt(0) lgkmcnt(0)" ::: "memory");
      }
      __builtin_amdgcn_s_barrier();

      const float* bb = xs[cur];
      long gr0 = row0 + (long)c * 64;
#pragma unroll 4
      for (int r = 0; r < 64; ++r) {
        long grc = gr0 + r;
        if (grc > N - 1) grc = N - 1;          // OOB-safe (b==0 there anyway)
        const float* ar = X + grc * 64 + wave * 16;  // uniform -> s_load_dwordx16
        float b = bb[r * 64 + lane];                 // stride-4B, conflict-free
#pragma unroll
        for (int i = 0; i < 16; ++i) acc[i] = fmaf(ar[i], b, acc[i]);
      }
      __builtin_amdgcn_s_barrier();   // protect buf before next-iter stage overwrites
    }
  }

  float* p = partials + (long)blockIdx.x * 4096;
#pragma unroll
  for (int i = 0; i < 16; ++i) p[(wave * 16 + i) * 64 + lane] = acc[i];
}

// ---------------- Kernel 2a/2b: two-stage reduce of partials -> G ----------------
__global__ __launch_bounds__(256) void k_reduce1(const float* __restrict__ partials,
                                                 float* __restrict__ P2, int nblk) {
  int g = blockIdx.x * 256 + threadIdx.x;  // 0..65535
  int e = g & 4095, s = g >> 12;           // 16 slices
  int p0 = (nblk * s) >> 4, p1 = (nblk * (s + 1)) >> 4;
  float sum = 0.f;
  for (int p = p0; p < p1; ++p) sum += partials[(long)p * 4096 + e];
  P2[g] = sum;
}

__global__ __launch_bounds__(256) void k_reduce2(const float* __restrict__ P2,
                                                 float* __restrict__ G) {
  int e = blockIdx.x * 256 + threadIdx.x;  // grid 16
  float sum = 0.f;
#pragma unroll
  for (int s = 0; s < 16; ++s) sum += P2[s * 4096 + e];
  G[e] = sum;
}

// ---------------- Kernel 3: Cholesky G = L L^T, Rinv = L^-T ----------------
__global__ __launch_bounds__(64) void k_cholinv(const float* __restrict__ G,
                                                float* __restrict__ Rinv) {
  __shared__ float A[64][65];
  __shared__ float Li[64][65];
  __shared__ float invd[64];
  const int t = threadIdx.x;

  for (int j = 0; j < 64; ++j) A[t][j] = G[t * 64 + j];
  __syncthreads();

  for (int k = 0; k < 64; ++k) {
    if (t == k) {
      float d = sqrtf(A[k][k]);
      A[k][k] = d;
      invd[k] = 1.f / d;               // one divide per k (hoisted)
    }
    __syncthreads();
    if (t > k) A[t][k] *= invd[k];
    __syncthreads();
    if (t > k) {
      float lik = A[t][k];
      for (int j = k + 1; j <= t; ++j) A[t][j] -= lik * A[j][k];  // j uniform, broadcast
    }
    __syncthreads();
  }

  // forward-substitute column t of Linv; diagonal sweep, no syncs needed
  // (thread t reads/writes only column t of Li)
  Li[t][t] = invd[t];
  for (int rr = 1; rr < 64; ++rr) {
    int r = t + rr;
    int rc = r < 64 ? r : 63;          // clamp keeps trip count uniform
    float s = 0.f;
    for (int m = 0; m < rr; ++m) s += A[rc][t + m] * Li[t + m][t];  // stride-66: conflict-free
    if (r < 64) Li[r][t] = -s * invd[rc];
  }
  __syncthreads();

  for (int j = 0; j < 64; ++j)
    Rinv[t * 64 + j] = (j >= t) ? Li[j][t] : 0.f;   // Rinv = Linv^T (upper)
}

// ---------------- Kernel 4: Q = X * Rinv, register-row, SMEM Rinv ----------------
// One thread per row. Triangular accumulation in 4 column blocks of 16
// (keeps live VGPRs ~ x[<=64] + q[16]). Rinv reads are uniform-address ->
// scalar loads (s_load_dwordx16), zero LDS.
__global__ __launch_bounds__(256) void k_apply(const float* __restrict__ X,
                                               const float* __restrict__ Rinv,
                                               float* __restrict__ Q, int N) {
  long row = (long)blockIdx.x * 256 + threadIdx.x;
  if (row >= N) return;
  const float* xr = X + row * 64;
  float* qr = Q + row * 64;
  float x[64];

#pragma unroll
  for (int cb = 0; cb < 4; ++cb) {
    // load x[16cb .. 16cb+16)
#pragma unroll
    for (int i = 0; i < 4; ++i)
      *reinterpret_cast<float4*>(&x[cb * 16 + i * 4]) =
          reinterpret_cast<const float4*>(xr)[cb * 4 + i];

    float q[16];
#pragma unroll
    for (int j = 0; j < 16; ++j) q[j] = 0.f;

#pragma unroll
    for (int k = 0; k < cb * 16 + 16; ++k) {     // triangular: k <= j_global
      float xk = x[k];
      int jlo = k - cb * 16; if (jlo < 0) jlo = 0;
#pragma unroll
      for (int j = 0; j < 16; ++j)
        if (j >= jlo)
          q[j] = fmaf(xk, Rinv[k * 64 + cb * 16 + j], q[j]);  // uniform -> s_load
    }

#pragma unroll
    for (int i = 0; i < 4; ++i)
      reinterpret_cast<float4*>(qr)[cb * 4 + i] =
          *reinterpret_cast<const float4*>(&q[i * 4]);
  }
}

extern "C" void kernel_launch(void* const* d_in, const int* in_sizes, int n_in,
                              void* d_out, int out_size, void* d_ws, size_t ws_size,
                              hipStream_t stream) {
  const float* X = (const float*)d_in[0];
  float* Q = (float*)d_out;
  const int N = in_sizes[0] / MDIM;

  float* ws = (float*)d_ws;
  float* G = ws;                 // 4096
  float* Rinv = ws + 4096;       // 4096
  float* P2 = ws + 8192;         // 65536
  float* partials = ws + 73728;  // nblk * 4096

  long avail = ((long)(ws_size / 4) - 73728) / 4096;
  int nblk = avail >= 1024 ? 1024 : (avail < 1 ? 1 : (int)avail);
  long per = (long)nblk * 64;
  int rpb = (int)(((N + per - 1) / per) * 64);   // rows/block, multiple of 64

  k_gram<<<nblk, 256, 0, stream>>>(X, partials, N, rpb);
  k_reduce1<<<256, 256, 0, stream>>>(partials, P2, nblk);
  k_reduce2<<<16, 256, 0, stream>>>(P2, G);
  k_cholinv<<<1, 64, 0, stream>>>(G, Rinv);
  k_apply<<<(N + 255) / 256, 256, 0, stream>>>(X, Rinv, Q, N);
}